// Round 16
// baseline (91.440 us; speedup 1.0000x reference)
//
#include <hip/hip_runtime.h>
#include <hip/hip_bf16.h>

#define C_DIM 256
#define G_DIM 16
#define P_DIM 9
#define OMD 432
#define OM_GS 28                // ushorts per group (27 used + 1 pad)
#define OM_RS 448               // 16 * 28 ushorts per row (896 B)
#define NCAT 768                // 256 (val) + 512 (om+dead) fused-GEMM cols
#define H_DIM 56
#define W_DIM 56
#define HW 3136
#define M_ROWS 25088            // 8 * HW
#define CX_BLOCKS 1568          // 49 * 4 * 8 transpose tiles

typedef __bf16 bf16x8 __attribute__((ext_vector_type(8)));
typedef float f32x4 __attribute__((ext_vector_type(4)));
typedef unsigned short ushort_t;

__device__ inline ushort_t f2bf(float f) {
  unsigned u = __float_as_uint(f);
  unsigned r = u + 0x7fffu + ((u >> 16) & 1u);   // RNE
  return (ushort_t)(r >> 16);
}

__device__ inline void gload_lds16(const void* g, void* l) {
  __builtin_amdgcn_global_load_lds(
      (const __attribute__((address_space(1))) void*)g,
      (__attribute__((address_space(3))) void*)l, 16, 0, 0);
}

// ---------------------------------------------------------------------------
// Fused input prep (single launch):
//  blocks [0, CX_BLOCKS): x (N,C,H,W) fp32 -> xp (N*HW, C) bf16, 64x64 tile
//  blocks [CX_BLOCKS, ..): weights -> wcat/ow bf16 + bcat f32
// ---------------------------------------------------------------------------
__global__ __launch_bounds__(256) void convert_xw(const float* __restrict__ x,
                                                  const float* __restrict__ vw,
                                                  const float* __restrict__ omw,
                                                  const float* __restrict__ owt,
                                                  const float* __restrict__ vb,
                                                  const float* __restrict__ omb,
                                                  ushort_t* __restrict__ xp,
                                                  ushort_t* __restrict__ wcat,
                                                  ushort_t* __restrict__ ow,
                                                  float* __restrict__ bcat) {
  __shared__ float t[64][69];
  const int bid = blockIdx.x;
  const int tid = threadIdx.x;
  if (bid < CX_BLOCKS) {
    const int bx = bid % 49;
    const int by = (bid / 49) & 3;
    const int n = bid / 196;
    const int pblk = bx * 64, cblk = by * 64;
    const int lc = tid >> 4;
    const int lp4 = (tid & 15) * 4;
#pragma unroll
    for (int i = 0; i < 4; ++i) {
      const int c = lc + i * 16;
      const f32x4 v = *(const f32x4*)&x[(size_t)(n * C_DIM + cblk + c) * HW + pblk + lp4];
#pragma unroll
      for (int j = 0; j < 4; ++j) t[c][lp4 + j] = v[j];
    }
    __syncthreads();
    const int p = tid >> 2;
    const int c0 = (tid & 3) * 16;
    bf16x8 o0, o1;
#pragma unroll
    for (int j = 0; j < 8; ++j) {
      o0[j] = (__bf16)t[c0 + j][p];
      o1[j] = (__bf16)t[c0 + 8 + j][p];
    }
    ushort_t* dst = &xp[(size_t)(n * HW + pblk + p) * C_DIM + cblk + c0];
    *(bf16x8*)dst = o0;
    *(bf16x8*)(dst + 8) = o1;
  } else {
    const int i = (bid - CX_BLOCKS) * 256 + tid;
    if (i < NCAT * C_DIM) {
      int row = i >> 8, c = i & 255;
      float v;
      if (row < 256) v = vw[i];
      else {
        int orow = row - 256;
        v = (orow < OMD) ? omw[orow * C_DIM + c] : 0.f;
      }
      wcat[i] = f2bf(v);
    } else if (i < NCAT * C_DIM + 65536) {
      int j = i - NCAT * C_DIM;
      ow[j] = f2bf(owt[j]);
    } else if (i < NCAT * C_DIM + 65536 + NCAT) {
      int j = i - NCAT * C_DIM - 65536;
      bcat[j] = (j < 256) ? vb[j] : ((j < 256 + OMD) ? omb[j - 256] : 0.f);
    }
  }
}

// ---------------------------------------------------------------------------
// bf16 MFMA GEMM, 64x128 tile, TRIPLE-buffered LDS + counted vmcnt,
// TWO row-tiles serially per block (16 K-steps): pipeline never drains
// between tiles; both epilogues at the end (stores never pollute the
// mid-loop counted vmcnt).  acc0/acc1 statically indexed (full unroll).
// 1D grid, bijective XCD chunk swizzle.
// MODE 0 (fused val+om): col<256 -> bf16 valb; col in [256,688) -> om16
//   GS28 slot = oc + oc/27 (ei==26 zero-fills group pad); col>=688 dead.
// MODE 1 (out): fp32 NCHW (n*256+col)*HW + p, f32x4 vector store over rg.
// ---------------------------------------------------------------------------
template <int MODE>
__global__ __launch_bounds__(256) void gemm_mfma(const ushort_t* __restrict__ A,
                                                 const ushort_t* __restrict__ B,
                                                 const float* __restrict__ bias,
                                                 void* __restrict__ Y0,
                                                 ushort_t* __restrict__ Y1,
                                                 int JB) {
  __shared__ ushort_t Asl[3][64 * 32];
  __shared__ ushort_t Bsl[3][128 * 32];
  const int tid = threadIdx.x;
  const int wave = tid >> 6;
  const int lane = tid & 63;
  // XCD chunk swizzle
  const int hb = blockIdx.x;
  const int chunk = gridDim.x >> 3;
  const int l = (hb & 7) * chunk + (hb >> 3);
  const int jb = l % JB;
  const int rb = l / JB;
  const int rblk = rb * 128;     // two 64-row tiles: rblk, rblk+64
  const int jblk = jb * 128;
  const int wm = wave >> 1, wn = wave & 1;
  const int lrow = lane & 15;
  const int lk8 = lane >> 4;

  f32x4 acc0[2][4], acc1[2][4];
#pragma unroll
  for (int i = 0; i < 2; ++i)
#pragma unroll
    for (int j = 0; j < 4; ++j) {
      acc0[i][j] = f32x4{0.f, 0.f, 0.f, 0.f};
      acc1[i][j] = f32x4{0.f, 0.f, 0.f, 0.f};
    }

  const int srow = tid >> 2;     // A row 0..63 / B row base
  const int skseg = tid & 3;

  // step s in [0,16): row-half = s>=8, k0 = (s&7)*32
#define STAGE(s_, buf_)                                                        \
  {                                                                            \
    const int arow = rblk + (((s_) >= 8) ? 64 : 0) + srow;                     \
    const int k0s = ((s_) & 7) * 32;                                           \
    gload_lds16(A + (size_t)arow * C_DIM + k0s + skseg * 8,                    \
                (char*)&Asl[buf_][0] + tid * 16);                              \
    _Pragma("unroll") for (int i = 0; i < 2; ++i) {                            \
      gload_lds16(B + (size_t)(jblk + srow + i * 64) * C_DIM + k0s + skseg * 8,\
                  (char*)&Bsl[buf_][0] + tid * 16 + i * 4096);                 \
    }                                                                          \
  }

  STAGE(0, 0);
  STAGE(1, 1);

#pragma unroll
  for (int t = 0; t < 16; ++t) {
    const int cur = t % 3;
    if (t < 15) {
      asm volatile("s_waitcnt vmcnt(3)" ::: "memory");
    } else {
      asm volatile("s_waitcnt vmcnt(0)" ::: "memory");
    }
    __builtin_amdgcn_s_barrier();
    __builtin_amdgcn_sched_barrier(0);
    if (t < 14) STAGE(t + 2, (t + 2) % 3);
    bf16x8 a[2], b[4];
#pragma unroll
    for (int mi = 0; mi < 2; ++mi)
      a[mi] = *(const bf16x8*)&Asl[cur][(wm * 32 + mi * 16 + lrow) * 32 + lk8 * 8];
#pragma unroll
    for (int nj = 0; nj < 4; ++nj)
      b[nj] = *(const bf16x8*)&Bsl[cur][(wn * 64 + nj * 16 + lrow) * 32 + lk8 * 8];
    if (t < 8) {
#pragma unroll
      for (int mi = 0; mi < 2; ++mi)
#pragma unroll
        for (int nj = 0; nj < 4; ++nj)
          acc0[mi][nj] = __builtin_amdgcn_mfma_f32_16x16x32_bf16(a[mi], b[nj], acc0[mi][nj], 0, 0, 0);
    } else {
#pragma unroll
      for (int mi = 0; mi < 2; ++mi)
#pragma unroll
        for (int nj = 0; nj < 4; ++nj)
          acc1[mi][nj] = __builtin_amdgcn_mfma_f32_16x16x32_bf16(a[mi], b[nj], acc1[mi][nj], 0, 0, 0);
    }
  }
#undef STAGE

#pragma unroll
  for (int tile = 0; tile < 2; ++tile) {
    f32x4(&acc)[2][4] = tile ? acc1 : acc0;
    const int rbase = rblk + tile * 64;
#pragma unroll
    for (int nj = 0; nj < 4; ++nj) {
      const int col = jblk + wn * 64 + nj * 16 + lrow;
      const float bs = bias[col];
      int slot = 0;
      bool om_write = false, pad_write = false;
      if (MODE == 0 && col >= 256) {
        const int oc = col - 256;
        if (oc < OMD) {
          const int gi = oc / 27;
          const int ei = oc - gi * 27;
          slot = oc + gi;
          om_write = true;
          pad_write = (ei == 26);
        }
      }
#pragma unroll
      for (int mi = 0; mi < 2; ++mi) {
        if (MODE == 1) {
          const int r0 = rbase + wm * 32 + mi * 16 + lk8 * 4;
          const int n = r0 / HW;
          const int p0 = r0 - n * HW;
          f32x4 vv;
#pragma unroll
          for (int rg = 0; rg < 4; ++rg) vv[rg] = acc[mi][nj][rg] + bs;
          *(f32x4*)&((float*)Y0)[(size_t)(n * C_DIM + col) * HW + p0] = vv;
        } else {
#pragma unroll
          for (int rg = 0; rg < 4; ++rg) {
            const int r = rbase + wm * 32 + mi * 16 + lk8 * 4 + rg;
            const float v = acc[mi][nj][rg] + bs;
            if (col < 256) {
              ((ushort_t*)Y0)[(size_t)r * C_DIM + col] = f2bf(v);
            } else if (om_write) {
              Y1[(size_t)r * OM_RS + slot] = f2bf(v);
              if (pad_write) Y1[(size_t)r * OM_RS + slot + 1] = 0;
            }
          }
        }
      }
    }
  }
}

// ---------------------------------------------------------------------------
// DCNv4 core, 4 ch/thread, 3-tap batched MLP (round-14 form, unchanged).
// ---------------------------------------------------------------------------
__device__ inline void acc4(float* acc, uint2 v, float wq) {
  const unsigned u0 = v.x, u1 = v.y;
  acc[0] = fmaf(wq, __uint_as_float(u0 << 16), acc[0]);
  acc[1] = fmaf(wq, __uint_as_float(u0 & 0xffff0000u), acc[1]);
  acc[2] = fmaf(wq, __uint_as_float(u1 << 16), acc[2]);
  acc[3] = fmaf(wq, __uint_as_float(u1 & 0xffff0000u), acc[3]);
}

__global__ __launch_bounds__(256) void dcn_core(const unsigned* __restrict__ val_u,
                                                const ushort_t* __restrict__ om16,
                                                unsigned* __restrict__ core_u) {
  const int bid = blockIdx.x;
  // bijective XCD swizzle: 6272 blocks = 8 * 784
  const int swz = (bid & 7) * 784 + (bid >> 3);
  const int tid = threadIdx.x;
  const int lane = tid & 63;
  const int wave = tid >> 6;     // pixel in block
  const int q = lane & 3;        // channel quarter (4 ch)
  const int g = lane >> 2;       // group
  const int r = swz * 4 + wave;
  const int n = r / HW;
  const int p = r - n * HW;
  const int h = p / W_DIM;
  const int w = p - h * W_DIM;

  // per-thread offsets/masks: 14 dwords = 28 bf16 (27 used)
  unsigned uw[14];
  const char* omp = (const char*)om16 + (size_t)r * (OM_RS * 2) + g * (OM_GS * 2);
#pragma unroll
  for (int i = 0; i < 7; ++i)
    *(uint2*)&uw[2 * i] = *(const uint2*)(omp + 8 * i);

  const unsigned* vb = val_u + (size_t)n * (HW * 128) + g * 8 + q * 2;

  float acc[4];
#pragma unroll
  for (int i = 0; i < 4; ++i) acc[i] = 0.f;

#pragma unroll
  for (int b = 0; b < 3; ++b) {
    int offv[3][4];
    float wqv[3][4];
#pragma unroll
    for (int i = 0; i < 3; ++i) {
      const int pp = b * 3 + i;
      const float offx = __uint_as_float(uw[pp] << 16);
      const float offy = __uint_as_float(uw[pp] & 0xffff0000u);
      const float lh_f = (float)(h - 1 + pp / 3) + offy;
      const float lw_f = (float)(w - 1 + pp % 3) + offx;
      const float h0f = floorf(lh_f);
      const float w0f = floorf(lw_f);
      const float lh = lh_f - h0f;
      const float lw = lw_f - w0f;
      const int h0 = (int)h0f;
      const int w0 = (int)w0f;
      const int h1 = h0 + 1;
      const int w1 = w0 + 1;
      const float hv0 = ((unsigned)h0 < 56u) ? 1.f : 0.f;
      const float hv1 = ((unsigned)h1 < 56u) ? 1.f : 0.f;
      const float wv0 = ((unsigned)w0 < 56u) ? 1.f : 0.f;
      const float wv1 = ((unsigned)w1 < 56u) ? 1.f : 0.f;
      const int h0c = min(max(h0, 0), H_DIM - 1);
      const int h1c = min(max(h1, 0), H_DIM - 1);
      const int w0c = min(max(w0, 0), W_DIM - 1);
      const int w1c = min(max(w1, 0), W_DIM - 1);
      const unsigned midx = 18 + pp;
      const unsigned mword = uw[midx >> 1];
      const float m =
          __uint_as_float((midx & 1) ? (mword & 0xffff0000u) : (mword << 16));
      wqv[i][0] = m * (1.f - lh) * (1.f - lw) * hv0 * wv0;
      wqv[i][1] = m * (1.f - lh) * lw * hv0 * wv1;
      wqv[i][2] = m * lh * (1.f - lw) * hv1 * wv0;
      wqv[i][3] = m * lh * lw * hv1 * wv1;
      offv[i][0] = (h0c * W_DIM + w0c) * 128;
      offv[i][1] = (h0c * W_DIM + w1c) * 128;
      offv[i][2] = (h1c * W_DIM + w0c) * 128;
      offv[i][3] = (h1c * W_DIM + w1c) * 128;
    }
    uint2 d[3][4];
#pragma unroll
    for (int i = 0; i < 3; ++i)
#pragma unroll
      for (int c = 0; c < 4; ++c)
        d[i][c] = *(const uint2*)&vb[offv[i][c]];
#pragma unroll
    for (int i = 0; i < 3; ++i)
#pragma unroll
      for (int c = 0; c < 4; ++c)
        acc4(acc, d[i][c], wqv[i][c]);
  }

  uint2 o;
  o.x = (unsigned)f2bf(acc[0]) | ((unsigned)f2bf(acc[1]) << 16);
  o.y = (unsigned)f2bf(acc[2]) | ((unsigned)f2bf(acc[3]) << 16);
  *(uint2*)&core_u[(size_t)r * 128 + g * 8 + q * 2] = o;
}

extern "C" void kernel_launch(void* const* d_in, const int* in_sizes, int n_in,
                              void* d_out, int out_size, void* d_ws, size_t ws_size,
                              hipStream_t stream) {
  const float* x       = (const float*)d_in[0];
  const float* value_w = (const float*)d_in[1];
  const float* value_b = (const float*)d_in[2];
  const float* om_w    = (const float*)d_in[3];
  const float* om_b    = (const float*)d_in[4];
  const float* out_w   = (const float*)d_in[5];
  const float* out_b   = (const float*)d_in[6];
  float* out = (float*)d_out;

  // workspace layout
  char* wsb = (char*)d_ws;
  ushort_t* om16  = (ushort_t*)wsb;                            // 25088*448*2 B
  ushort_t* xp    = om16 + (size_t)M_ROWS * OM_RS;
  ushort_t* valb  = xp + (size_t)M_ROWS * C_DIM;
  ushort_t* coreb = valb + (size_t)M_ROWS * C_DIM;
  ushort_t* wcat  = coreb + (size_t)M_ROWS * C_DIM;            // 768*256 bf16
  ushort_t* ow    = wcat + NCAT * C_DIM;                       // 256*256 bf16
  float* bcat     = (float*)(ow + C_DIM * C_DIM);              // 768 f32

  dim3 blk(256);
  const int cw_elems = NCAT * C_DIM + 65536 + NCAT;
  const int cw_blocks = (cw_elems + 255) / 256;
  convert_xw<<<dim3(CX_BLOCKS + cw_blocks), blk, 0, stream>>>(
      x, value_w, om_w, out_w, value_b, om_b, xp, wcat, ow, bcat);
  // fused: val (cols 0..255) + om (cols 256..687); 688..767 dead
  gemm_mfma<0><<<dim3(6 * 196), blk, 0, stream>>>(xp, wcat, bcat, valb, om16, 6);
  // deformable sampling (4 ch/thread, 3-tap MLP batches)
  dcn_core<<<dim3(M_ROWS / 4), blk, 0, stream>>>((const unsigned*)valb, om16, (unsigned*)coreb);
  // out = core @ out_w.T + out_b   (fp32 NCHW)
  gemm_mfma<1><<<dim3(2 * 196), blk, 0, stream>>>(coreb, ow, out_b, out, nullptr, 2);
}

// Round 18
// 83.685 us; speedup vs baseline: 1.0927x; 1.0927x over previous
//
#include <hip/hip_runtime.h>
#include <hip/hip_bf16.h>

#define C_DIM 256
#define G_DIM 16
#define P_DIM 9
#define OMD 432
#define OM_GS 28                // ushorts per group (27 used + 1 pad)
#define OM_RS 448               // 16 * 28 ushorts per row (896 B)
#define NCAT 768                // 256 (val) + 512 (om+dead) fused-GEMM cols
#define H_DIM 56
#define W_DIM 56
#define HW 3136
#define M_ROWS 25088            // 8 * HW
#define CX_BLOCKS 1568          // 49 * 4 * 8 transpose tiles

typedef __bf16 bf16x8 __attribute__((ext_vector_type(8)));
typedef float f32x4 __attribute__((ext_vector_type(4)));
typedef unsigned short ushort_t;

__device__ inline ushort_t f2bf(float f) {
  unsigned u = __float_as_uint(f);
  unsigned r = u + 0x7fffu + ((u >> 16) & 1u);   // RNE
  return (ushort_t)(r >> 16);
}

__device__ inline void gload_lds16(const void* g, void* l) {
  __builtin_amdgcn_global_load_lds(
      (const __attribute__((address_space(1))) void*)g,
      (__attribute__((address_space(3))) void*)l, 16, 0, 0);
}

// ---------------------------------------------------------------------------
// Fused input prep (single launch):
//  blocks [0, CX_BLOCKS): x (N,C,H,W) fp32 -> xp (N*HW, C) bf16, 64x64 tile
//  blocks [CX_BLOCKS, ..): weights -> wcat/ow bf16 + bcat f32
// ---------------------------------------------------------------------------
__global__ __launch_bounds__(256) void convert_xw(const float* __restrict__ x,
                                                  const float* __restrict__ vw,
                                                  const float* __restrict__ omw,
                                                  const float* __restrict__ owt,
                                                  const float* __restrict__ vb,
                                                  const float* __restrict__ omb,
                                                  ushort_t* __restrict__ xp,
                                                  ushort_t* __restrict__ wcat,
                                                  ushort_t* __restrict__ ow,
                                                  float* __restrict__ bcat) {
  __shared__ float t[64][69];
  const int bid = blockIdx.x;
  const int tid = threadIdx.x;
  if (bid < CX_BLOCKS) {
    const int bx = bid % 49;
    const int by = (bid / 49) & 3;
    const int n = bid / 196;
    const int pblk = bx * 64, cblk = by * 64;
    const int lc = tid >> 4;
    const int lp4 = (tid & 15) * 4;
#pragma unroll
    for (int i = 0; i < 4; ++i) {
      const int c = lc + i * 16;
      const f32x4 v = *(const f32x4*)&x[(size_t)(n * C_DIM + cblk + c) * HW + pblk + lp4];
#pragma unroll
      for (int j = 0; j < 4; ++j) t[c][lp4 + j] = v[j];
    }
    __syncthreads();
    const int p = tid >> 2;
    const int c0 = (tid & 3) * 16;
    bf16x8 o0, o1;
#pragma unroll
    for (int j = 0; j < 8; ++j) {
      o0[j] = (__bf16)t[c0 + j][p];
      o1[j] = (__bf16)t[c0 + 8 + j][p];
    }
    ushort_t* dst = &xp[(size_t)(n * HW + pblk + p) * C_DIM + cblk + c0];
    *(bf16x8*)dst = o0;
    *(bf16x8*)(dst + 8) = o1;
  } else {
    const int i = (bid - CX_BLOCKS) * 256 + tid;
    if (i < NCAT * C_DIM) {
      int row = i >> 8, c = i & 255;
      float v;
      if (row < 256) v = vw[i];
      else {
        int orow = row - 256;
        v = (orow < OMD) ? omw[orow * C_DIM + c] : 0.f;
      }
      wcat[i] = f2bf(v);
    } else if (i < NCAT * C_DIM + 65536) {
      int j = i - NCAT * C_DIM;
      ow[j] = f2bf(owt[j]);
    } else if (i < NCAT * C_DIM + 65536 + NCAT) {
      int j = i - NCAT * C_DIM - 65536;
      bcat[j] = (j < 256) ? vb[j] : ((j < 256 + OMD) ? omb[j - 256] : 0.f);
    }
  }
}

// ---------------------------------------------------------------------------
// bf16 MFMA GEMM, 64x128 tile, TRIPLE-buffered LDS + counted vmcnt:
//   per iter: wait vmcnt(3) -> barrier -> STAGE(t+2) -> ds_read+MFMA(t)
// 1D grid, bijective XCD chunk swizzle; JB col-blocks share A-panel in-chunk.
// MODE 0 (fused val+om): col<256 -> bf16 valb; col in [256,688) -> om16
//   GS28 slot = oc + oc/27 (ei==26 zero-fills group pad); col>=688 dead.
// MODE 1 (out): fp32 NCHW (n*256+col)*HW + p, f32x4 vector store over rg.
// ---------------------------------------------------------------------------
template <int MODE>
__global__ __launch_bounds__(256) void gemm_mfma(const ushort_t* __restrict__ A,
                                                 const ushort_t* __restrict__ B,
                                                 const float* __restrict__ bias,
                                                 void* __restrict__ Y0,
                                                 ushort_t* __restrict__ Y1,
                                                 int JB) {
  __shared__ ushort_t Asl[3][64 * 32];
  __shared__ ushort_t Bsl[3][128 * 32];
  const int tid = threadIdx.x;
  const int wave = tid >> 6;
  const int lane = tid & 63;
  // XCD chunk swizzle
  const int hb = blockIdx.x;
  const int chunk = gridDim.x >> 3;
  const int l = (hb & 7) * chunk + (hb >> 3);
  const int jb = l % JB;
  const int rb = l / JB;
  const int rblk = rb * 64;
  const int jblk = jb * 128;
  const int wm = wave >> 1, wn = wave & 1;
  const int lrow = lane & 15;
  const int lk8 = lane >> 4;

  f32x4 acc[2][4];
#pragma unroll
  for (int i = 0; i < 2; ++i)
#pragma unroll
    for (int j = 0; j < 4; ++j) acc[i][j] = f32x4{0.f, 0.f, 0.f, 0.f};

  const int srow = tid >> 2;     // A row 0..63 / B row base
  const int skseg = tid & 3;

  // A: 1 load (64x32), B: 2 loads (128x32); 3 gloads per STAGE
#define STAGE(k0_, buf_)                                                       \
  {                                                                            \
    gload_lds16(A + (size_t)(rblk + srow) * C_DIM + (k0_) + skseg * 8,         \
                (char*)&Asl[buf_][0] + tid * 16);                              \
    _Pragma("unroll") for (int i = 0; i < 2; ++i) {                            \
      gload_lds16(B + (size_t)(jblk + srow + i * 64) * C_DIM + (k0_) + skseg * 8, \
                  (char*)&Bsl[buf_][0] + tid * 16 + i * 4096);                 \
    }                                                                          \
  }

  STAGE(0, 0);
  STAGE(32, 1);

#pragma unroll
  for (int t = 0; t < 8; ++t) {
    const int cur = t % 3;
    if (t < 7) {
      asm volatile("s_waitcnt vmcnt(3)" ::: "memory");
    } else {
      asm volatile("s_waitcnt vmcnt(0)" ::: "memory");
    }
    __builtin_amdgcn_s_barrier();
    __builtin_amdgcn_sched_barrier(0);
    if (t < 6) STAGE((t + 2) * 32, (t + 2) % 3);
    bf16x8 a[2], b[4];
#pragma unroll
    for (int mi = 0; mi < 2; ++mi)
      a[mi] = *(const bf16x8*)&Asl[cur][(wm * 32 + mi * 16 + lrow) * 32 + lk8 * 8];
#pragma unroll
    for (int nj = 0; nj < 4; ++nj)
      b[nj] = *(const bf16x8*)&Bsl[cur][(wn * 64 + nj * 16 + lrow) * 32 + lk8 * 8];
#pragma unroll
    for (int mi = 0; mi < 2; ++mi)
#pragma unroll
      for (int nj = 0; nj < 4; ++nj)
        acc[mi][nj] = __builtin_amdgcn_mfma_f32_16x16x32_bf16(a[mi], b[nj], acc[mi][nj], 0, 0, 0);
  }
#undef STAGE

#pragma unroll
  for (int nj = 0; nj < 4; ++nj) {
    const int col = jblk + wn * 64 + nj * 16 + lrow;
    const float bs = bias[col];
    int slot = 0;
    bool om_write = false, pad_write = false;
    if (MODE == 0 && col >= 256) {
      const int oc = col - 256;
      if (oc < OMD) {
        const int gi = oc / 27;
        const int ei = oc - gi * 27;
        slot = oc + gi;
        om_write = true;
        pad_write = (ei == 26);
      }
    }
#pragma unroll
    for (int mi = 0; mi < 2; ++mi) {
      if (MODE == 1) {
        const int r0 = rblk + wm * 32 + mi * 16 + lk8 * 4;
        const int n = r0 / HW;
        const int p0 = r0 - n * HW;
        f32x4 vv;
#pragma unroll
        for (int rg = 0; rg < 4; ++rg) vv[rg] = acc[mi][nj][rg] + bs;
        *(f32x4*)&((float*)Y0)[(size_t)(n * C_DIM + col) * HW + p0] = vv;
      } else {
#pragma unroll
        for (int rg = 0; rg < 4; ++rg) {
          const int r = rblk + wm * 32 + mi * 16 + lk8 * 4 + rg;
          const float v = acc[mi][nj][rg] + bs;
          if (col < 256) {
            ((ushort_t*)Y0)[(size_t)r * C_DIM + col] = f2bf(v);
          } else if (om_write) {
            Y1[(size_t)r * OM_RS + slot] = f2bf(v);
            if (pad_write) Y1[(size_t)r * OM_RS + slot + 1] = 0;
          }
        }
      }
    }
  }
}

// ---------------------------------------------------------------------------
// DCNv4 core, 4 ch/thread, 3-tap batched MLP: per batch compute 12 addresses
// + 12 weights (pure VALU), issue 12 uint2 loads, then 12 acc4.  All arrays
// statically indexed (stay in registers).  Wave = 1 pixel; lane = g*4+q.
// ---------------------------------------------------------------------------
__device__ inline void acc4(float* acc, uint2 v, float wq) {
  const unsigned u0 = v.x, u1 = v.y;
  acc[0] = fmaf(wq, __uint_as_float(u0 << 16), acc[0]);
  acc[1] = fmaf(wq, __uint_as_float(u0 & 0xffff0000u), acc[1]);
  acc[2] = fmaf(wq, __uint_as_float(u1 << 16), acc[2]);
  acc[3] = fmaf(wq, __uint_as_float(u1 & 0xffff0000u), acc[3]);
}

__global__ __launch_bounds__(256) void dcn_core(const unsigned* __restrict__ val_u,
                                                const ushort_t* __restrict__ om16,
                                                unsigned* __restrict__ core_u) {
  const int bid = blockIdx.x;
  // bijective XCD swizzle: 6272 blocks = 8 * 784
  const int swz = (bid & 7) * 784 + (bid >> 3);
  const int tid = threadIdx.x;
  const int lane = tid & 63;
  const int wave = tid >> 6;     // pixel in block
  const int q = lane & 3;        // channel quarter (4 ch)
  const int g = lane >> 2;       // group
  const int r = swz * 4 + wave;
  const int n = r / HW;
  const int p = r - n * HW;
  const int h = p / W_DIM;
  const int w = p - h * W_DIM;

  // per-thread offsets/masks: 14 dwords = 28 bf16 (27 used)
  unsigned uw[14];
  const char* omp = (const char*)om16 + (size_t)r * (OM_RS * 2) + g * (OM_GS * 2);
#pragma unroll
  for (int i = 0; i < 7; ++i)
    *(uint2*)&uw[2 * i] = *(const uint2*)(omp + 8 * i);

  const unsigned* vb = val_u + (size_t)n * (HW * 128) + g * 8 + q * 2;

  float acc[4];
#pragma unroll
  for (int i = 0; i < 4; ++i) acc[i] = 0.f;

#pragma unroll
  for (int b = 0; b < 3; ++b) {
    int offv[3][4];
    float wqv[3][4];
#pragma unroll
    for (int i = 0; i < 3; ++i) {
      const int pp = b * 3 + i;
      const float offx = __uint_as_float(uw[pp] << 16);
      const float offy = __uint_as_float(uw[pp] & 0xffff0000u);
      const float lh_f = (float)(h - 1 + pp / 3) + offy;
      const float lw_f = (float)(w - 1 + pp % 3) + offx;
      const float h0f = floorf(lh_f);
      const float w0f = floorf(lw_f);
      const float lh = lh_f - h0f;
      const float lw = lw_f - w0f;
      const int h0 = (int)h0f;
      const int w0 = (int)w0f;
      const int h1 = h0 + 1;
      const int w1 = w0 + 1;
      const float hv0 = ((unsigned)h0 < 56u) ? 1.f : 0.f;
      const float hv1 = ((unsigned)h1 < 56u) ? 1.f : 0.f;
      const float wv0 = ((unsigned)w0 < 56u) ? 1.f : 0.f;
      const float wv1 = ((unsigned)w1 < 56u) ? 1.f : 0.f;
      const int h0c = min(max(h0, 0), H_DIM - 1);
      const int h1c = min(max(h1, 0), H_DIM - 1);
      const int w0c = min(max(w0, 0), W_DIM - 1);
      const int w1c = min(max(w1, 0), W_DIM - 1);
      const unsigned midx = 18 + pp;
      const unsigned mword = uw[midx >> 1];
      const float m =
          __uint_as_float((midx & 1) ? (mword & 0xffff0000u) : (mword << 16));
      wqv[i][0] = m * (1.f - lh) * (1.f - lw) * hv0 * wv0;
      wqv[i][1] = m * (1.f - lh) * lw * hv0 * wv1;
      wqv[i][2] = m * lh * (1.f - lw) * hv1 * wv0;
      wqv[i][3] = m * lh * lw * hv1 * wv1;
      offv[i][0] = (h0c * W_DIM + w0c) * 128;
      offv[i][1] = (h0c * W_DIM + w1c) * 128;
      offv[i][2] = (h1c * W_DIM + w0c) * 128;
      offv[i][3] = (h1c * W_DIM + w1c) * 128;
    }
    uint2 d[3][4];
#pragma unroll
    for (int i = 0; i < 3; ++i)
#pragma unroll
      for (int c = 0; c < 4; ++c)
        d[i][c] = *(const uint2*)&vb[offv[i][c]];
#pragma unroll
    for (int i = 0; i < 3; ++i)
#pragma unroll
      for (int c = 0; c < 4; ++c)
        acc4(acc, d[i][c], wqv[i][c]);
  }

  uint2 o;
  o.x = (unsigned)f2bf(acc[0]) | ((unsigned)f2bf(acc[1]) << 16);
  o.y = (unsigned)f2bf(acc[2]) | ((unsigned)f2bf(acc[3]) << 16);
  *(uint2*)&core_u[(size_t)r * 128 + g * 8 + q * 2] = o;
}

extern "C" void kernel_launch(void* const* d_in, const int* in_sizes, int n_in,
                              void* d_out, int out_size, void* d_ws, size_t ws_size,
                              hipStream_t stream) {
  const float* x       = (const float*)d_in[0];
  const float* value_w = (const float*)d_in[1];
  const float* value_b = (const float*)d_in[2];
  const float* om_w    = (const float*)d_in[3];
  const float* om_b    = (const float*)d_in[4];
  const float* out_w   = (const float*)d_in[5];
  const float* out_b   = (const float*)d_in[6];
  float* out = (float*)d_out;

  // workspace layout
  char* wsb = (char*)d_ws;
  ushort_t* om16  = (ushort_t*)wsb;                            // 25088*448*2 B
  ushort_t* xp    = om16 + (size_t)M_ROWS * OM_RS;
  ushort_t* valb  = xp + (size_t)M_ROWS * C_DIM;
  ushort_t* coreb = valb + (size_t)M_ROWS * C_DIM;
  ushort_t* wcat  = coreb + (size_t)M_ROWS * C_DIM;            // 768*256 bf16
  ushort_t* ow    = wcat + NCAT * C_DIM;                       // 256*256 bf16
  float* bcat     = (float*)(ow + C_DIM * C_DIM);              // 768 f32

  dim3 blk(256);
  const int cw_elems = NCAT * C_DIM + 65536 + NCAT;
  const int cw_blocks = (cw_elems + 255) / 256;
  convert_xw<<<dim3(CX_BLOCKS + cw_blocks), blk, 0, stream>>>(
      x, value_w, om_w, out_w, value_b, om_b, xp, wcat, ow, bcat);
  // fused: val (cols 0..255) + om (cols 256..687); 688..767 dead
  gemm_mfma<0><<<dim3(6 * 392), blk, 0, stream>>>(xp, wcat, bcat, valb, om16, 6);
  // deformable sampling (4 ch/thread, 3-tap MLP batches)
  dcn_core<<<dim3(M_ROWS / 4), blk, 0, stream>>>((const unsigned*)valb, om16, (unsigned*)coreb);
  // out = core @ out_w.T + out_b   (fp32 NCHW)
  gemm_mfma<1><<<dim3(2 * 392), blk, 0, stream>>>(coreb, ow, out_b, out, nullptr, 2);
}